// Round 6
// baseline (472.076 us; speedup 1.0000x reference)
//
#include <hip/hip_runtime.h>
#include <hip/hip_bf16.h>
#include <stdint.h>

// ---------------------------------------------------------------------------
// SCINet forward (B=32,T=1024,C=128,HID=512, 3 levels, N_SPLITS=2) on gfx950.
// fp16 MFMA GEMMs, fp32 carry path. R6: conv1 streams WEIGHTS directly to
// VGPRs (global->reg, double-buffered across taps) -- the per-lane fragment
// pattern is identical in LDS and global, so the LDS round-trip for B was
// pure overhead. K-loop now has ZERO barriers / vmcnt drains. A stays
// LDS-staged (XOR-swizzled via producers; staging linear, rule #21).
// ---------------------------------------------------------------------------

static constexpr int B_ = 32, T_ = 1024, C_ = 128, HID_ = 512;
static constexpr int K1_ = 5, K2_ = 3;

typedef __attribute__((ext_vector_type(8))) _Float16 half8;
typedef __attribute__((ext_vector_type(4))) float f32x4;

__device__ __forceinline__ unsigned short f2h(float f) {
    _Float16 h = (_Float16)f;                     // v_cvt_f16_f32 (RNE)
    return __builtin_bit_cast(unsigned short, h);
}

__device__ __forceinline__ void gload16(const void* g, void* l) {
    __builtin_amdgcn_global_load_lds(
        (const __attribute__((address_space(1))) unsigned int*)g,
        (__attribute__((address_space(3))) unsigned int*)l, 16, 0, 0);
}

// ---------------------------------------------------------------------------
// Weight prep: fp32 [slab][CIN][COUT] -> fp16 [slab][COUT][CIN].
// SWZ: XOR-swizzle ci within 128-chunks by (co&7) (for LDS-staged weights,
// conv2). Non-SWZ: linear (conv1 reads weights straight to VGPRs).
// ---------------------------------------------------------------------------
template<int CIN, int COUT, bool SWZ>
__global__ __launch_bounds__(256)
void wprep_k(const float* __restrict__ win1, unsigned short* __restrict__ wout1,
             const float* __restrict__ win2, unsigned short* __restrict__ wout2,
             int nhalf) {
    constexpr int TA = CIN / 64, TB = COUT / 64;
    int blk = blockIdx.x;
    int tb = blk % TB;
    int ta = (blk / TB) % TA;
    int s  = blk / (TA * TB);
    const float* win;
    unsigned short* wout;
    if (s < nhalf) { win = win1; wout = wout1; }
    else           { win = win2; wout = wout2; s -= nhalf; }
    __shared__ float tile[64][65];
    const float* src = win + (size_t)s * CIN * COUT;
    unsigned short* dst = wout + (size_t)s * CIN * COUT;
    int cl = threadIdx.x & 63;
    int rw = threadIdx.x >> 6;
    for (int r = rw; r < 64; r += 4)
        tile[r][cl] = src[(size_t)(ta * 64 + r) * COUT + tb * 64 + cl];
    __syncthreads();
    for (int r = rw; r < 64; r += 4) {
        int co = tb * 64 + r;
        int ci = ta * 64 + cl;
        int ciw = SWZ ? ((ci & ~127) | ((ci & 127) ^ ((co & 7) << 3))) : ci;
        dst[(size_t)co * CIN + ciw] = f2h(tile[cl][r]);
    }
}

// ---------------------------------------------------------------------------
// Split (level 0 only): x [B][1024][C] fp32 -> actb [2][B][512][swz(C)] fp16.
// actb swizzle key = (u+4)&7  (conv1 LDS row = u - t0 + 4, t0 % 8 == 0).
// ---------------------------------------------------------------------------
__global__ __launch_bounds__(256)
void split_k(const float* __restrict__ cur, unsigned short* __restrict__ outb,
             int Ls) {
    int idx = blockIdx.x * 256 + threadIdx.x;       // 1,048,576 total (rows*32)
    int row = idx >> 5;
    int cq  = (idx & 31) << 2;
    int BLs = B_ * Ls;
    int g  = row / BLs;
    int r2 = row - g * BLs;
    int b  = r2 / Ls;
    int u  = r2 - b * Ls;
    int p = g >> 1, i = g & 1;
    const float4 v = *(const float4*)(cur +
        ((size_t)(p * B_ + b) * (2 * Ls) + 2 * u + i) * C_ + cq);
    ushort4 o;
    o.x = f2h(v.x); o.y = f2h(v.y); o.z = f2h(v.z); o.w = f2h(v.w);
    int cqw = cq ^ (((u + 4) & 7) << 3);            // 8B-aligned XOR (bits 3-5)
    *(ushort4*)(outb + (size_t)row * C_ + cqw) = o;
}

// ---------------------------------------------------------------------------
// conv1: out = leaky( causal_conv_K5( actb[g^1] , W[widx] ) + b1[widx] )
// tile 128 rows x 64 cols, 4 waves (2 row x 2 col; wave tile 64x32).
// A [132][128] fp16 in LDS (33KB, staged once, ONE barrier). B (weights)
// streamed per-tap global->VGPR, double-buffered b0/b1 (statically unrolled).
// No barriers in K-loop. Output hidb pre-swizzled for conv2 (key (t+2)&7).
// ---------------------------------------------------------------------------
__global__ __launch_bounds__(256, 3)
void conv1_k(const unsigned short* __restrict__ actb,
             const unsigned short* __restrict__ wL,   // [widx][5][512][128] linear
             const float* __restrict__ bias,          // [widx][512]
             unsigned short* __restrict__ hid,        // [G][B][Ls][512swz]
             const unsigned short* __restrict__ zp,
             int Ls, int RT, int idxbase) {
    __shared__ unsigned short smemA[132 * 128];

    const int tid = threadIdx.x;
    const int lane = tid & 63;
    const int w = tid >> 6;
    const int wr = w >> 1, wc = w & 1;

    int blk = blockIdx.x;
    const int ct = blk & 7;                       // 8 col tiles of 64
    int t1 = blk >> 3;
    const int rt = t1 % RT;
    const int g  = t1 / RT;
    const int n0 = ct * 64;
    const int rowstart = rt * 128;
    const int b  = rowstart / Ls;
    const int t0 = rowstart - b * Ls;

    const int gin  = g ^ 1;
    const int widx = (idxbase + (g >> 1)) * 2 + (g & 1);

    const char* inb = (const char*)(actb + (size_t)(gin * B_ + b) * Ls * C_);
    const float* bptr = bias + (size_t)widx * HID_;

    // B fragment per-lane base: co = n0 + wc*32 + n*16 + (lane&15),
    // k = ks*32 + (lane>>4)*8 ; addr = ((kk*HID + co)*C + k)
    const unsigned short* wlane = wL + (size_t)widx * (K1_ * HID_ * C_)
                                + (size_t)(n0 + wc * 32 + (lane & 15)) * C_
                                + ((lane >> 4) << 3);

    half8 b0[8], b1[8];                           // [n*4 + ks]
    // issue tap-0 B loads (covered by the same vmcnt(0) as A staging)
#pragma unroll
    for (int n = 0; n < 2; ++n)
#pragma unroll
        for (int ks = 0; ks < 4; ++ks)
            b0[n * 4 + ks] = *(const half8*)(wlane + (size_t)n * 16 * C_ + ks * 32);

    // stage A once: rows t0-4 .. t0+127 (132 rows x 256 B = 33 chunks of 1KB)
    for (int ch = w; ch < 33; ch += 4) {
        int q = ch * 1024 + lane * 16;
        int r = q >> 8;
        int cb = q & 255;
        int t = t0 - 4 + r;
        const char* src = (t >= 0) ? inb + (size_t)t * 256 + cb
                                   : (const char*)zp + cb;
        gload16(src, (char*)smemA + ch * 1024);
    }
    asm volatile("s_waitcnt vmcnt(0)" ::: "memory");
    __syncthreads();

    f32x4 acc[4][2];
#pragma unroll
    for (int m = 0; m < 4; ++m)
#pragma unroll
        for (int n = 0; n < 2; ++n) acc[m][n] = (f32x4){0.f, 0.f, 0.f, 0.f};

    // one tap: prefetch next tap's B into bn, compute with bc
    auto tap = [&](const int kk, half8 (&bc)[8], half8 (&bn)[8]) {
        if (kk < K1_ - 1) {
            const unsigned short* wn = wlane + (size_t)(kk + 1) * HID_ * C_;
#pragma unroll
            for (int n = 0; n < 2; ++n)
#pragma unroll
                for (int ks = 0; ks < 4; ++ks)
                    bn[n * 4 + ks] = *(const half8*)(wn + (size_t)n * 16 * C_ + ks * 32);
        }
#pragma unroll
        for (int ks = 0; ks < 4; ++ks) {
            half8 aF[4];
            const int cole = ks * 32 + ((lane >> 4) << 3);
#pragma unroll
            for (int m = 0; m < 4; ++m) {
                int ar = kk + wr * 64 + m * 16 + (lane & 15);
                aF[m] = *(const half8*)(smemA + ar * 128 + (cole ^ ((ar & 7) << 3)));
            }
#pragma unroll
            for (int m = 0; m < 4; ++m) {
                acc[m][0] = __builtin_amdgcn_mfma_f32_16x16x32_f16(
                    aF[m], bc[ks], acc[m][0], 0, 0, 0);
                acc[m][1] = __builtin_amdgcn_mfma_f32_16x16x32_f16(
                    aF[m], bc[4 + ks], acc[m][1], 0, 0, 0);
            }
        }
    };
    tap(0, b0, b1);
    tap(1, b1, b0);
    tap(2, b0, b1);
    tap(3, b1, b0);
    tap(4, b0, b1);

    unsigned short* outp = hid + ((size_t)(g * B_ + b) * Ls + t0) * HID_;
#pragma unroll
    for (int n = 0; n < 2; ++n) {
        int co = n0 + wc * 32 + n * 16 + (lane & 15);
        float bv = bptr[co];
#pragma unroll
        for (int m = 0; m < 4; ++m) {
            int u0 = wr * 64 + m * 16 + ((lane >> 4) << 2);
#pragma unroll
            for (int q = 0; q < 4; ++q) {
                float v = acc[m][n][q] + bv;
                v = (v > 0.f) ? v : 0.01f * v;            // LeakyReLU
                int t = t0 + u0 + q;
                int cow = (co & ~127) | ((co & 127) ^ (((t + 2) & 7) << 3));
                outp[(size_t)(u0 + q) * HID_ + cow] = f2h(v);
            }
        }
    }
}

// ---------------------------------------------------------------------------
// conv2: s = tanh( causal_conv_K3( hid[g], W2[widx] ) + b2[widx] )
// EPI 0 (gate):  mul = cur[p][b][2u+i][c] * exp(s) -> mulf (f32) + actb (fp16)
// EPI 1 (mid):   val = mulf +/- s -> nxt (f32) + next-level actb (fp16, fused
//                split: g'=2g+(u&1), u'=u>>1, swz key (u'+4)&7)
// EPI 2 (last):  val = mulf +/- s -> d_out[b][tau][c], tau = u | revbits(g)
// tile 64 rows x 128 cols, 4 waves (2x2, wave tile 32x64), K = 3*512 chunked.
// LDS 49KB -> 3 blocks/CU.
// ---------------------------------------------------------------------------
template<int EPI>
__global__ __launch_bounds__(256, 3)
void conv2_k(const unsigned short* __restrict__ hid,
             const unsigned short* __restrict__ wT,   // [widx][3][128][512swz]
             const float* __restrict__ bias,          // [widx][128]
             const float* __restrict__ cur,           // EPI==0
             float* __restrict__ mulf,
             unsigned short* __restrict__ actb,       // EPI==0: gate out (swz)
             float* __restrict__ nxt,                 // EPI==1 out
             unsigned short* __restrict__ actn,       // EPI==1: next-lvl actb
             float* __restrict__ dout,                // EPI==2 out
             const unsigned short* __restrict__ zp,
             int Ls, int RT, int idxbase) {
    __shared__ unsigned short smemA[66 * 128];
    __shared__ unsigned short smemB[128 * 128];

    const int tid = threadIdx.x;
    const int lane = tid & 63;
    const int w = tid >> 6;
    const int wr = w >> 1, wc = w & 1;

    int blk = blockIdx.x;
    const int rt = blk % RT;
    const int g  = blk / RT;
    const int rowstart = rt * 64;
    const int b  = rowstart / Ls;
    const int t0 = rowstart - b * Ls;
    const int widx = (idxbase + (g >> 1)) * 2 + (g & 1);

    const char* inb = (const char*)(hid + (size_t)(g * B_ + b) * Ls * HID_);
    const char* wb  = (const char*)(wT + (size_t)widx * (K2_ * C_ * HID_));
    const float* bptr = bias + (size_t)widx * C_;

    f32x4 acc[2][4];
#pragma unroll
    for (int m = 0; m < 2; ++m)
#pragma unroll
        for (int n = 0; n < 4; ++n) acc[m][n] = (f32x4){0.f, 0.f, 0.f, 0.f};

    for (int ck = 0; ck < 4; ++ck) {           // 4 chunks of 128 over CIN=512
        if (ck) __syncthreads();
        // stage A chunk: rows t0-2 .. t0+63 (66 rows x 256 B = 16896 B)
        for (int ch = w; ch < 17; ch += 4) {
            int q = ch * 1024 + lane * 16;
            if (q < 16896) {
                int r = q >> 8;
                int cb = q & 255;
                int t = t0 - 2 + r;
                const char* src = (t >= 0)
                    ? inb + (size_t)t * 1024 + ck * 256 + cb
                    : (const char*)zp + cb;
                gload16(src, (char*)smemA + ch * 1024);
            }
        }
        for (int kk = 0; kk < K2_; ++kk) {
            if (kk) __syncthreads();
            const char* wt = wb + (size_t)kk * C_ * HID_ * 2;
            for (int ch = w; ch < 32; ch += 4) {
                int q = ch * 1024 + lane * 16;
                int co = q >> 8;
                int cb = q & 255;
                gload16(wt + (size_t)co * 1024 + ck * 256 + cb,
                        (char*)smemB + ch * 1024);
            }
            asm volatile("s_waitcnt vmcnt(0)" ::: "memory");
            __syncthreads();

#pragma unroll
            for (int ks = 0; ks < 4; ++ks) {
                half8 aF[2], bF[4];
                const int cole = ks * 32 + ((lane >> 4) << 3);
#pragma unroll
                for (int m = 0; m < 2; ++m) {
                    int ar = kk + wr * 32 + m * 16 + (lane & 15);
                    aF[m] = *(const half8*)(smemA + ar * 128 + (cole ^ ((ar & 7) << 3)));
                }
#pragma unroll
                for (int n = 0; n < 4; ++n) {
                    int br = wc * 64 + n * 16 + (lane & 15);
                    bF[n] = *(const half8*)(smemB + br * 128 + (cole ^ ((br & 7) << 3)));
                }
#pragma unroll
                for (int m = 0; m < 2; ++m)
#pragma unroll
                    for (int n = 0; n < 4; ++n)
                        acc[m][n] = __builtin_amdgcn_mfma_f32_16x16x32_f16(
                            aF[m], bF[n], acc[m][n], 0, 0, 0);
            }
        }
    }

    const size_t rowb = (size_t)(g * B_ + b) * Ls + t0;
    const int p_ = g >> 1, i_ = g & 1;
    const int Ls2 = Ls >> 1;
#pragma unroll
    for (int n = 0; n < 4; ++n) {
        int c = wc * 64 + n * 16 + (lane & 15);
        float bv = bptr[c];
#pragma unroll
        for (int m = 0; m < 2; ++m) {
            int u0 = wr * 32 + m * 16 + ((lane >> 4) << 2);
#pragma unroll
            for (int q = 0; q < 4; ++q) {
                float v = acc[m][n][q] + bv;
                float xc = fminf(fmaxf(v, -15.f), 15.f);
                float e2 = __expf(2.f * xc);
                float th = (e2 - 1.f) / (e2 + 1.f);        // tanh
                size_t ro = rowb + (size_t)(u0 + q);
                int u = t0 + u0 + q;                       // local split time
                if (EPI == 0) {
                    float sv = cur[((size_t)(p_ * B_ + b) * (2 * Ls) + 2 * u + i_) * C_ + c];
                    float mv = sv * __expf(th);
                    mulf[ro * C_ + c] = mv;
                    int cw = c ^ (((u + 4) & 7) << 3);     // actb swizzle
                    actb[ro * C_ + cw] = f2h(mv);
                } else {
                    float mv = mulf[ro * C_ + c];
                    float val = (i_ == 0) ? (mv + th) : (mv - th);
                    if (EPI == 1) {
                        nxt[ro * C_ + c] = val;
                        // fused split for next level
                        int gq = g * 2 + (u & 1);
                        int uq = u >> 1;
                        int cw = c ^ (((uq + 4) & 7) << 3);
                        actn[((size_t)(gq * B_ + b) * Ls2 + uq) * C_ + cw] = f2h(val);
                    } else {
                        // fused rev_split gather (last level, Ls = 128)
                        int tau = u | (((g >> 2) & 1) << 7) | (((g >> 1) & 1) << 8)
                                    | ((g & 1) << 9);
                        dout[((size_t)b * T_ + tau) * C_ + c] = val;
                    }
                }
            }
        }
    }
}

// ---------------------------------------------------------------------------
extern "C" void kernel_launch(void* const* d_in, const int* in_sizes, int n_in,
                              void* d_out, int out_size, void* d_ws, size_t ws_size,
                              hipStream_t stream) {
    const float* x   = (const float*)d_in[0];
    const float* mw1 = (const float*)d_in[1];
    const float* mb1 = (const float*)d_in[2];
    const float* mw2 = (const float*)d_in[3];
    const float* mb2 = (const float*)d_in[4];
    const float* aw1 = (const float*)d_in[5];
    const float* ab1 = (const float*)d_in[6];
    const float* aw2 = (const float*)d_in[7];
    const float* ab2 = (const float*)d_in[8];

    char* ws = (char*)d_ws;
    size_t off = 0;
    auto alloc = [&](size_t sz) {
        char* p = ws + off;
        off += (sz + 255) & ~(size_t)255;
        return p;
    };
    unsigned short* zp   = (unsigned short*)alloc(8192);
    unsigned short* w1m  = (unsigned short*)alloc((size_t)14 * 5 * 512 * 128 * 2);
    unsigned short* w1a  = (unsigned short*)alloc((size_t)14 * 5 * 512 * 128 * 2);
    unsigned short* w2m  = (unsigned short*)alloc((size_t)14 * 3 * 128 * 512 * 2);
    unsigned short* w2a  = (unsigned short*)alloc((size_t)14 * 3 * 128 * 512 * 2);
    float* bufA          = (float*)alloc((size_t)4194304 * 4);
    float* bufB          = (float*)alloc((size_t)4194304 * 4);
    unsigned short* actb = (unsigned short*)alloc((size_t)4194304 * 2);
    unsigned short* hidb = (unsigned short*)alloc((size_t)16777216 * 2);
    float* mulf          = (float*)alloc((size_t)4194304 * 4);
    (void)ws_size; (void)n_in; (void)in_sizes; (void)out_size;

    hipMemsetAsync(zp, 0, 8192, stream);

    // weight prep: w1 linear (conv1 reg-streams), w2 swizzled (conv2 LDS)
    wprep_k<128, 512, false><<<2240, 256, 0, stream>>>(mw1, w1m, aw1, w1a, 70);
    wprep_k<512, 128, true ><<<1344, 256, 0, stream>>>(mw2, w2m, aw2, w2a, 42);

    // level-0 split (levels 1,2 are fused into conv2-EPI1)
    split_k<<<4096, 256, 0, stream>>>(x, actb, 512);

    for (int lvl = 0; lvl < 3; ++lvl) {
        const int P = 1 << lvl;
        const int G = 2 * P;
        const int Ls = (1024 >> lvl) >> 1;
        const int idxbase = P - 1;
        const float* cur = (lvl == 0) ? x : ((lvl == 1) ? bufA : bufB);
        float* nxt = (lvl == 1) ? bufB : bufA;
        const int RT1 = Ls / 4;   // 128-row tiles: B*Ls/128
        const int RT2 = Ls / 2;   // 64-row tiles:  B*Ls/64

        conv1_k<<<G * RT1 * 8, 256, 0, stream>>>(actb, w1m, mb1, hidb, zp,
                                                 Ls, RT1, idxbase);
        conv2_k<0><<<G * RT2, 256, 0, stream>>>(hidb, w2m, mb2, cur, mulf,
                                                actb, nullptr, nullptr, nullptr,
                                                zp, Ls, RT2, idxbase);
        conv1_k<<<G * RT1 * 8, 256, 0, stream>>>(actb, w1a, ab1, hidb, zp,
                                                 Ls, RT1, idxbase);
        if (lvl < 2) {
            conv2_k<1><<<G * RT2, 256, 0, stream>>>(hidb, w2a, ab2, nullptr, mulf,
                                                    nullptr, nxt, actb, nullptr,
                                                    zp, Ls, RT2, idxbase);
        } else {
            conv2_k<2><<<G * RT2, 256, 0, stream>>>(hidb, w2a, ab2, nullptr, mulf,
                                                    nullptr, nullptr, nullptr,
                                                    (float*)d_out,
                                                    zp, Ls, RT2, idxbase);
        }
    }
}

// Round 7
// 378.604 us; speedup vs baseline: 1.2469x; 1.2469x over previous
//
#include <hip/hip_runtime.h>
#include <hip/hip_bf16.h>
#include <stdint.h>

// ---------------------------------------------------------------------------
// SCINet forward (B=32,T=1024,C=128,HID=512, 3 levels, N_SPLITS=2) on gfx950.
// fp16 MFMA GEMMs, fp32 carry path, XOR bank-conflict swizzle baked into all
// producers (LDS staging stays linear, rule #21). R7: conv1 back to LDS B
// staging (R6's global->VGPR stream was compiler-defeated, VGPR=68 proved
// loads were sunk to use) + T3 minimum-2-phase: B double-buffered in LDS,
// STAGE(next tap) issued BEFORE compute(cur tap), one vmcnt(0)+barrier per
// tap with ~0 drain cost. conv2 unchanged (single-variable change).
// ---------------------------------------------------------------------------

static constexpr int B_ = 32, T_ = 1024, C_ = 128, HID_ = 512;
static constexpr int K1_ = 5, K2_ = 3;

typedef __attribute__((ext_vector_type(8))) _Float16 half8;
typedef __attribute__((ext_vector_type(4))) float f32x4;

__device__ __forceinline__ unsigned short f2h(float f) {
    _Float16 h = (_Float16)f;                     // v_cvt_f16_f32 (RNE)
    return __builtin_bit_cast(unsigned short, h);
}

__device__ __forceinline__ void gload16(const void* g, void* l) {
    __builtin_amdgcn_global_load_lds(
        (const __attribute__((address_space(1))) unsigned int*)g,
        (__attribute__((address_space(3))) unsigned int*)l, 16, 0, 0);
}

// ---------------------------------------------------------------------------
// Weight prep: fp32 [slab][CIN][COUT] -> fp16 [slab][COUT][swz(CIN)].
// Two sources (mul/add) in one launch. Swizzle key = co&7 within each
// 128-element ci chunk: ci' = (ci & ~127) | ((ci&127) ^ ((co&7)<<3)).
// ---------------------------------------------------------------------------
template<int CIN, int COUT>
__global__ __launch_bounds__(256)
void wprep_k(const float* __restrict__ win1, unsigned short* __restrict__ wout1,
             const float* __restrict__ win2, unsigned short* __restrict__ wout2,
             int nhalf) {
    constexpr int TA = CIN / 64, TB = COUT / 64;
    int blk = blockIdx.x;
    int tb = blk % TB;
    int ta = (blk / TB) % TA;
    int s  = blk / (TA * TB);
    const float* win;
    unsigned short* wout;
    if (s < nhalf) { win = win1; wout = wout1; }
    else           { win = win2; wout = wout2; s -= nhalf; }
    __shared__ float tile[64][65];
    const float* src = win + (size_t)s * CIN * COUT;
    unsigned short* dst = wout + (size_t)s * CIN * COUT;
    int cl = threadIdx.x & 63;
    int rw = threadIdx.x >> 6;
    for (int r = rw; r < 64; r += 4)
        tile[r][cl] = src[(size_t)(ta * 64 + r) * COUT + tb * 64 + cl];
    __syncthreads();
    for (int r = rw; r < 64; r += 4) {
        int co = tb * 64 + r;
        int ci = ta * 64 + cl;
        int ciw = (ci & ~127) | ((ci & 127) ^ ((co & 7) << 3));
        dst[(size_t)co * CIN + ciw] = f2h(tile[cl][r]);
    }
}

// ---------------------------------------------------------------------------
// Split (level 0 only): x [B][1024][C] fp32 -> actb [2][B][512][swz(C)] fp16.
// actb swizzle key = (u+4)&7  (conv1 LDS row = u - t0 + 4, t0 % 8 == 0).
// ---------------------------------------------------------------------------
__global__ __launch_bounds__(256)
void split_k(const float* __restrict__ cur, unsigned short* __restrict__ outb,
             int Ls) {
    int idx = blockIdx.x * 256 + threadIdx.x;       // 1,048,576 total (rows*32)
    int row = idx >> 5;
    int cq  = (idx & 31) << 2;
    int BLs = B_ * Ls;
    int g  = row / BLs;
    int r2 = row - g * BLs;
    int b  = r2 / Ls;
    int u  = r2 - b * Ls;
    int p = g >> 1, i = g & 1;
    const float4 v = *(const float4*)(cur +
        ((size_t)(p * B_ + b) * (2 * Ls) + 2 * u + i) * C_ + cq);
    ushort4 o;
    o.x = f2h(v.x); o.y = f2h(v.y); o.z = f2h(v.z); o.w = f2h(v.w);
    int cqw = cq ^ (((u + 4) & 7) << 3);            // 8B-aligned XOR (bits 3-5)
    *(ushort4*)(outb + (size_t)row * C_ + cqw) = o;
}

// ---------------------------------------------------------------------------
// conv1: out = leaky( causal_conv_K5( actb[g^1] , W[widx] ) + b1[widx] )
// tile 128 rows x 64 cols, 4 waves (2 row x 2 col; wave tile 64x32).
// LDS: A [132][128] (33KB, staged once) + B dbuf 2x[64][128] (2x16KB).
// 2-phase: STAGE_B(next tap) issued BEFORE compute(cur tap); one
// vmcnt(0)+barrier per tap, drain hidden under ds_read+MFMA.
// Sources pre-swizzled; staging linear; reads XOR col with (row&7)<<3.
// Output hidb pre-swizzled for conv2 (key (t+2)&7).
// ---------------------------------------------------------------------------
__global__ __launch_bounds__(256, 2)
void conv1_k(const unsigned short* __restrict__ actb,
             const unsigned short* __restrict__ wT,   // [widx][5][512][128swz]
             const float* __restrict__ bias,          // [widx][512]
             unsigned short* __restrict__ hid,        // [G][B][Ls][512swz]
             const unsigned short* __restrict__ zp,
             int Ls, int RT, int idxbase) {
    __shared__ unsigned short smemA[132 * 128];
    __shared__ unsigned short smemB[2][64 * 128];

    const int tid = threadIdx.x;
    const int lane = tid & 63;
    const int w = tid >> 6;
    const int wr = w >> 1, wc = w & 1;

    int blk = blockIdx.x;
    const int ct = blk & 7;                       // 8 col tiles of 64
    int t1 = blk >> 3;
    const int rt = t1 % RT;
    const int g  = t1 / RT;
    const int n0 = ct * 64;
    const int rowstart = rt * 128;
    const int b  = rowstart / Ls;
    const int t0 = rowstart - b * Ls;

    const int gin  = g ^ 1;
    const int widx = (idxbase + (g >> 1)) * 2 + (g & 1);

    const char* inb = (const char*)(actb + (size_t)(gin * B_ + b) * Ls * C_);
    const char* wb  = (const char*)(wT + (size_t)widx * (K1_ * HID_ * C_));
    const float* bptr = bias + (size_t)widx * HID_;

    // per-thread B staging address pieces (16 chunks of 1KB, 4 per wave)
    const int bq  = lane * 16;                    // byte in 1KB chunk
    const int bco = bq >> 8;                      // +co within chunk group
    const int bcb = bq & 255;                     // byte within co row

    // stage B tap 0 into buf 0
#pragma unroll
    for (int ch0 = 0; ch0 < 4; ++ch0) {
        int ch = w + ch0 * 4;
        gload16(wb + (size_t)(n0 + ch * 4 + bco) * 256 + bcb,
                (char*)smemB[0] + ch * 1024);
    }
    // stage A once: rows t0-4 .. t0+127 (132 rows x 256 B = 33 chunks of 1KB)
    for (int ch = w; ch < 33; ch += 4) {
        int q = ch * 1024 + lane * 16;
        int r = q >> 8;
        int cb = q & 255;
        int t = t0 - 4 + r;
        const char* src = (t >= 0) ? inb + (size_t)t * 256 + cb
                                   : (const char*)zp + cb;
        gload16(src, (char*)smemA + ch * 1024);
    }
    asm volatile("s_waitcnt vmcnt(0)" ::: "memory");
    __syncthreads();

    f32x4 acc[4][2];
#pragma unroll
    for (int m = 0; m < 4; ++m)
#pragma unroll
        for (int n = 0; n < 2; ++n) acc[m][n] = (f32x4){0.f, 0.f, 0.f, 0.f};

#pragma unroll
    for (int kk = 0; kk < K1_; ++kk) {
        // phase 1: issue next tap's B stage into the other buffer
        if (kk < K1_ - 1) {
            const char* wt = wb + (size_t)(kk + 1) * HID_ * C_ * 2;
#pragma unroll
            for (int ch0 = 0; ch0 < 4; ++ch0) {
                int ch = w + ch0 * 4;
                gload16(wt + (size_t)(n0 + ch * 4 + bco) * 256 + bcb,
                        (char*)smemB[(kk + 1) & 1] + ch * 1024);
            }
        }
        // phase 2: compute current tap from smemB[kk&1]
        const unsigned short* sB = smemB[kk & 1];
#pragma unroll
        for (int ks = 0; ks < 4; ++ks) {
            half8 aF[4], bF[2];
            const int cole = ks * 32 + ((lane >> 4) << 3);
#pragma unroll
            for (int m = 0; m < 4; ++m) {
                int ar = kk + wr * 64 + m * 16 + (lane & 15);
                aF[m] = *(const half8*)(smemA + ar * 128 + (cole ^ ((ar & 7) << 3)));
            }
#pragma unroll
            for (int n = 0; n < 2; ++n) {
                int br = wc * 32 + n * 16 + (lane & 15);
                bF[n] = *(const half8*)(sB + br * 128 + (cole ^ ((br & 7) << 3)));
            }
#pragma unroll
            for (int m = 0; m < 4; ++m) {
                acc[m][0] = __builtin_amdgcn_mfma_f32_16x16x32_f16(
                    aF[m], bF[0], acc[m][0], 0, 0, 0);
                acc[m][1] = __builtin_amdgcn_mfma_f32_16x16x32_f16(
                    aF[m], bF[1], acc[m][1], 0, 0, 0);
            }
        }
        // phase 3: ensure next buffer is resident before anyone reads it
        if (kk < K1_ - 1) __syncthreads();   // syncthreads drains vmcnt(0) too
    }

    unsigned short* outp = hid + ((size_t)(g * B_ + b) * Ls + t0) * HID_;
#pragma unroll
    for (int n = 0; n < 2; ++n) {
        int co = n0 + wc * 32 + n * 16 + (lane & 15);
        float bv = bptr[co];
#pragma unroll
        for (int m = 0; m < 4; ++m) {
            int u0 = wr * 64 + m * 16 + ((lane >> 4) << 2);
#pragma unroll
            for (int q = 0; q < 4; ++q) {
                float v = acc[m][n][q] + bv;
                v = (v > 0.f) ? v : 0.01f * v;            // LeakyReLU
                int t = t0 + u0 + q;
                int cow = (co & ~127) | ((co & 127) ^ (((t + 2) & 7) << 3));
                outp[(size_t)(u0 + q) * HID_ + cow] = f2h(v);
            }
        }
    }
}

// ---------------------------------------------------------------------------
// conv2: s = tanh( causal_conv_K3( hid[g], W2[widx] ) + b2[widx] )
// EPI 0 (gate):  mul = cur[p][b][2u+i][c] * exp(s) -> mulf (f32) + actb (fp16)
// EPI 1 (mid):   val = mulf +/- s -> nxt (f32) + next-level actb (fp16, fused
//                split: g'=2g+(u&1), u'=u>>1, swz key (u'+4)&7)
// EPI 2 (last):  val = mulf +/- s -> d_out[b][tau][c], tau = u | revbits(g)
// tile 64 rows x 128 cols, 4 waves (2x2, wave tile 32x64), K = 3*512 chunked.
// LDS 49KB -> 3 blocks/CU.
// ---------------------------------------------------------------------------
template<int EPI>
__global__ __launch_bounds__(256, 3)
void conv2_k(const unsigned short* __restrict__ hid,
             const unsigned short* __restrict__ wT,   // [widx][3][128][512swz]
             const float* __restrict__ bias,          // [widx][128]
             const float* __restrict__ cur,           // EPI==0
             float* __restrict__ mulf,
             unsigned short* __restrict__ actb,       // EPI==0: gate out (swz)
             float* __restrict__ nxt,                 // EPI==1 out
             unsigned short* __restrict__ actn,       // EPI==1: next-lvl actb
             float* __restrict__ dout,                // EPI==2 out
             const unsigned short* __restrict__ zp,
             int Ls, int RT, int idxbase) {
    __shared__ unsigned short smemA[66 * 128];
    __shared__ unsigned short smemB[128 * 128];

    const int tid = threadIdx.x;
    const int lane = tid & 63;
    const int w = tid >> 6;
    const int wr = w >> 1, wc = w & 1;

    int blk = blockIdx.x;
    const int rt = blk % RT;
    const int g  = blk / RT;
    const int rowstart = rt * 64;
    const int b  = rowstart / Ls;
    const int t0 = rowstart - b * Ls;
    const int widx = (idxbase + (g >> 1)) * 2 + (g & 1);

    const char* inb = (const char*)(hid + (size_t)(g * B_ + b) * Ls * HID_);
    const char* wb  = (const char*)(wT + (size_t)widx * (K2_ * C_ * HID_));
    const float* bptr = bias + (size_t)widx * C_;

    f32x4 acc[2][4];
#pragma unroll
    for (int m = 0; m < 2; ++m)
#pragma unroll
        for (int n = 0; n < 4; ++n) acc[m][n] = (f32x4){0.f, 0.f, 0.f, 0.f};

    for (int ck = 0; ck < 4; ++ck) {           // 4 chunks of 128 over CIN=512
        if (ck) __syncthreads();
        // stage A chunk: rows t0-2 .. t0+63 (66 rows x 256 B = 16896 B)
        for (int ch = w; ch < 17; ch += 4) {
            int q = ch * 1024 + lane * 16;
            if (q < 16896) {
                int r = q >> 8;
                int cb = q & 255;
                int t = t0 - 2 + r;
                const char* src = (t >= 0)
                    ? inb + (size_t)t * 1024 + ck * 256 + cb
                    : (const char*)zp + cb;
                gload16(src, (char*)smemA + ch * 1024);
            }
        }
        for (int kk = 0; kk < K2_; ++kk) {
            if (kk) __syncthreads();
            const char* wt = wb + (size_t)kk * C_ * HID_ * 2;
            for (int ch = w; ch < 32; ch += 4) {
                int q = ch * 1024 + lane * 16;
                int co = q >> 8;
                int cb = q & 255;
                gload16(wt + (size_t)co * 1024 + ck * 256 + cb,
                        (char*)smemB + ch * 1024);
            }
            asm volatile("s_waitcnt vmcnt(0)" ::: "memory");
            __syncthreads();

#pragma unroll
            for (int ks = 0; ks < 4; ++ks) {
                half8 aF[2], bF[4];
                const int cole = ks * 32 + ((lane >> 4) << 3);
#pragma unroll
                for (int m = 0; m < 2; ++m) {
                    int ar = kk + wr * 32 + m * 16 + (lane & 15);
                    aF[m] = *(const half8*)(smemA + ar * 128 + (cole ^ ((ar & 7) << 3)));
                }
#pragma unroll
                for (int n = 0; n < 4; ++n) {
                    int br = wc * 64 + n * 16 + (lane & 15);
                    bF[n] = *(const half8*)(smemB + br * 128 + (cole ^ ((br & 7) << 3)));
                }
#pragma unroll
                for (int m = 0; m < 2; ++m)
#pragma unroll
                    for (int n = 0; n < 4; ++n)
                        acc[m][n] = __builtin_amdgcn_mfma_f32_16x16x32_f16(
                            aF[m], bF[n], acc[m][n], 0, 0, 0);
            }
        }
    }

    const size_t rowb = (size_t)(g * B_ + b) * Ls + t0;
    const int p_ = g >> 1, i_ = g & 1;
    const int Ls2 = Ls >> 1;
#pragma unroll
    for (int n = 0; n < 4; ++n) {
        int c = wc * 64 + n * 16 + (lane & 15);
        float bv = bptr[c];
#pragma unroll
        for (int m = 0; m < 2; ++m) {
            int u0 = wr * 32 + m * 16 + ((lane >> 4) << 2);
#pragma unroll
            for (int q = 0; q < 4; ++q) {
                float v = acc[m][n][q] + bv;
                float xc = fminf(fmaxf(v, -15.f), 15.f);
                float e2 = __expf(2.f * xc);
                float th = (e2 - 1.f) / (e2 + 1.f);        // tanh
                size_t ro = rowb + (size_t)(u0 + q);
                int u = t0 + u0 + q;                       // local split time
                if (EPI == 0) {
                    float sv = cur[((size_t)(p_ * B_ + b) * (2 * Ls) + 2 * u + i_) * C_ + c];
                    float mv = sv * __expf(th);
                    mulf[ro * C_ + c] = mv;
                    int cw = c ^ (((u + 4) & 7) << 3);     // actb swizzle
                    actb[ro * C_ + cw] = f2h(mv);
                } else {
                    float mv = mulf[ro * C_ + c];
                    float val = (i_ == 0) ? (mv + th) : (mv - th);
                    if (EPI == 1) {
                        nxt[ro * C_ + c] = val;
                        // fused split for next level
                        int gq = g * 2 + (u & 1);
                        int uq = u >> 1;
                        int cw = c ^ (((uq + 4) & 7) << 3);
                        actn[((size_t)(gq * B_ + b) * Ls2 + uq) * C_ + cw] = f2h(val);
                    } else {
                        // fused rev_split gather (last level, Ls = 128)
                        int tau = u | (((g >> 2) & 1) << 7) | (((g >> 1) & 1) << 8)
                                    | ((g & 1) << 9);
                        dout[((size_t)b * T_ + tau) * C_ + c] = val;
                    }
                }
            }
        }
    }
}

// ---------------------------------------------------------------------------
extern "C" void kernel_launch(void* const* d_in, const int* in_sizes, int n_in,
                              void* d_out, int out_size, void* d_ws, size_t ws_size,
                              hipStream_t stream) {
    const float* x   = (const float*)d_in[0];
    const float* mw1 = (const float*)d_in[1];
    const float* mb1 = (const float*)d_in[2];
    const float* mw2 = (const float*)d_in[3];
    const float* mb2 = (const float*)d_in[4];
    const float* aw1 = (const float*)d_in[5];
    const float* ab1 = (const float*)d_in[6];
    const float* aw2 = (const float*)d_in[7];
    const float* ab2 = (const float*)d_in[8];

    char* ws = (char*)d_ws;
    size_t off = 0;
    auto alloc = [&](size_t sz) {
        char* p = ws + off;
        off += (sz + 255) & ~(size_t)255;
        return p;
    };
    unsigned short* zp   = (unsigned short*)alloc(8192);
    unsigned short* w1m  = (unsigned short*)alloc((size_t)14 * 5 * 512 * 128 * 2);
    unsigned short* w1a  = (unsigned short*)alloc((size_t)14 * 5 * 512 * 128 * 2);
    unsigned short* w2m  = (unsigned short*)alloc((size_t)14 * 3 * 128 * 512 * 2);
    unsigned short* w2a  = (unsigned short*)alloc((size_t)14 * 3 * 128 * 512 * 2);
    float* bufA          = (float*)alloc((size_t)4194304 * 4);
    float* bufB          = (float*)alloc((size_t)4194304 * 4);
    unsigned short* actb = (unsigned short*)alloc((size_t)4194304 * 2);
    unsigned short* hidb = (unsigned short*)alloc((size_t)16777216 * 2);
    float* mulf          = (float*)alloc((size_t)4194304 * 4);
    (void)ws_size; (void)n_in; (void)in_sizes; (void)out_size;

    hipMemsetAsync(zp, 0, 8192, stream);

    // weight prep: transpose + fp16 + bank-conflict swizzle (2 launches)
    wprep_k<128, 512><<<2240, 256, 0, stream>>>(mw1, w1m, aw1, w1a, 70);
    wprep_k<512, 128><<<1344, 256, 0, stream>>>(mw2, w2m, aw2, w2a, 42);

    // level-0 split (levels 1,2 are fused into conv2-EPI1)
    split_k<<<4096, 256, 0, stream>>>(x, actb, 512);

    for (int lvl = 0; lvl < 3; ++lvl) {
        const int P = 1 << lvl;
        const int G = 2 * P;
        const int Ls = (1024 >> lvl) >> 1;
        const int idxbase = P - 1;
        const float* cur = (lvl == 0) ? x : ((lvl == 1) ? bufA : bufB);
        float* nxt = (lvl == 1) ? bufB : bufA;
        const int RT1 = Ls / 4;   // 128-row tiles: B*Ls/128
        const int RT2 = Ls / 2;   // 64-row tiles:  B*Ls/64

        conv1_k<<<G * RT1 * 8, 256, 0, stream>>>(actb, w1m, mb1, hidb, zp,
                                                 Ls, RT1, idxbase);
        conv2_k<0><<<G * RT2, 256, 0, stream>>>(hidb, w2m, mb2, cur, mulf,
                                                actb, nullptr, nullptr, nullptr,
                                                zp, Ls, RT2, idxbase);
        conv1_k<<<G * RT1 * 8, 256, 0, stream>>>(actb, w1a, ab1, hidb, zp,
                                                 Ls, RT1, idxbase);
        if (lvl < 2) {
            conv2_k<1><<<G * RT2, 256, 0, stream>>>(hidb, w2a, ab2, nullptr, mulf,
                                                    nullptr, nxt, actb, nullptr,
                                                    zp, Ls, RT2, idxbase);
        } else {
            conv2_k<2><<<G * RT2, 256, 0, stream>>>(hidb, w2a, ab2, nullptr, mulf,
                                                    nullptr, nullptr, nullptr,
                                                    (float*)d_out,
                                                    zp, Ls, RT2, idxbase);
        }
    }
}